// Round 7
// baseline (5578.342 us; speedup 1.0000x reference)
//
#include <hip/hip_runtime.h>
#include <stdint.h>
#include <stddef.h>

// ===================== problem constants =====================
// B=32 S=1024 C=12 E=256 H=512 V=50000 CS=128 T=50
#define NB   32
#define NS   1024
#define NC   12
#define NE   256
#define NH   512
#define NT   50
#define NWRD 32768          // B*S
#define MC   1024           // 4*E  (char gate rows)
#define RW   2048           // 4*H  (word gate rows)
#define KW   512            // 2*E

// ===================== types / helpers =====================
typedef short bf16x8 __attribute__((ext_vector_type(8)));
typedef short bf16x4 __attribute__((ext_vector_type(4)));
typedef float f32x4  __attribute__((ext_vector_type(4)));
typedef unsigned int u32x4 __attribute__((ext_vector_type(4)));

#define MFMA16(a,b,c) __builtin_amdgcn_mfma_f32_16x16x32_bf16(a, b, c, 0, 0, 0)

__device__ __forceinline__ float bf2f(short u){
  return __uint_as_float(((uint32_t)(uint16_t)u) << 16);
}
__device__ __forceinline__ short f2bf(float f){
  uint32_t u = __float_as_uint(f);
  uint32_t r = (u + 0x7FFFu + ((u >> 16) & 1u)) >> 16;  // RNE
  return (short)r;
}
__device__ __forceinline__ float sigf(float x){
  float e = __expf(-fabsf(x));
  float s = 1.0f / (1.0f + e);
  return x >= 0.0f ? s : 1.0f - s;
}
__device__ __forceinline__ float tanh_f(float x){
  float e = __expf(-2.0f * fabsf(x));
  float r = (1.0f - e) / (1.0f + e);
  return x >= 0.0f ? r : -r;
}
__device__ __forceinline__ uint32_t agent_ld(const uint32_t* p){
  return __hip_atomic_load(p, __ATOMIC_RELAXED, __HIP_MEMORY_SCOPE_AGENT);
}
__device__ __forceinline__ void agent_st(uint32_t* p, uint32_t v){
  __hip_atomic_store(p, v, __ATOMIC_RELAXED, __HIP_MEMORY_SCOPE_AGENT);
}

// ===================== prep: PEb = char_emb @ Wc_ih^T + bc (gate-interleaved) =====================
__global__ __launch_bounds__(256) void k_prep_pe(
    const float* __restrict__ char_emb, const float* __restrict__ Wc_ih,
    const float* __restrict__ bc, float* __restrict__ PEb)
{
  __shared__ float ce[NE];
  int a = blockIdx.x, tid = threadIdx.x;
  ce[tid] = char_emb[a * NE + tid];
  __syncthreads();
  int j = tid;
  float acc[4];
  #pragma unroll
  for (int g = 0; g < 4; ++g) acc[g] = 0.0f;
  for (int k = 0; k < NE; ++k) {
    float c = ce[k];
    #pragma unroll
    for (int g = 0; g < 4; ++g)
      acc[g] += c * Wc_ih[(size_t)(g * NE + j) * NE + k];
  }
  float4 o;
  o.x = acc[0] + bc[0 * NE + j];
  o.y = acc[1] + bc[1 * NE + j];
  o.z = acc[2] + bc[2 * NE + j];
  o.w = acc[3] + bc[3 * NE + j];
  *(float4*)&PEb[(size_t)a * MC + j * 4] = o;
}

// ===================== prep: weight convert + gate-interleave =====================
__global__ __launch_bounds__(256) void k_prep_w(
    const float* __restrict__ Wc_hh, const float* __restrict__ Ww_ih,
    const float* __restrict__ Ww_hh, const float* __restrict__ bw,
    short* __restrict__ WhhC, short* __restrict__ WihW,
    short* __restrict__ WhhW, float* __restrict__ bwI)
{
  int r = blockIdx.x;            // 0..2047
  int j = r >> 2, g = r & 3, tid = threadIdx.x;
  if (r < MC) {                  // char Whh: [1024][256]
    float v = Wc_hh[(size_t)(g * NE + j) * NE + tid];
    WhhC[(size_t)r * NE + tid] = f2bf(v);
  }
  #pragma unroll
  for (int kk = 0; kk < 2; ++kk) {
    int k = tid + kk * 256;
    WihW[(size_t)r * KW + k] = f2bf(Ww_ih[(size_t)(g * NH + j) * KW + k]);
    WhhW[(size_t)r * NH + k] = f2bf(Ww_hh[(size_t)(g * NH + j) * NH + k]);
  }
  if (tid == 0) bwI[r] = bw[g * NH + j];
}

// ===================== char step 0 (h=c=0): pure gather + cell =====================
__global__ __launch_bounds__(256) void k_char0(
    const int* __restrict__ char_idx, const float* __restrict__ PEb,
    float* __restrict__ c_state, short* __restrict__ h_out)
{
  int w = blockIdx.x, j = threadIdx.x;
  int idx = char_idx[w * NC + 0];
  float4 pe = *(const float4*)&PEb[(size_t)idx * MC + j * 4];
  float c = sigf(pe.x) * tanh_f(pe.z);          // sig(i)*tanh(g), c_prev=0
  float h = sigf(pe.w) * tanh_f(c);             // sig(o)*tanh(c)
  c_state[(size_t)w * NE + j] = c;
  h_out[(size_t)w * NE + j] = f2bf(h);
}

// ===================== generic MFMA GEMM: D[r][n] = A[r][:]·B[n][:], fused epilogue =====================
template<int KDIM, int EPI>
__global__ __launch_bounds__(256) void gemm_epi(
    const short* __restrict__ Amat, const short* __restrict__ Bmat,
    const float* __restrict__ PEb, const int* __restrict__ char_idx, int tstep,
    float* __restrict__ c_state, short* __restrict__ h_out,
    const float* __restrict__ bias, short* __restrict__ pw_out)
{
  __shared__ __align__(16) short As[128 * 64];
  __shared__ __align__(16) short Bs[128 * 64];
  const int tid = threadIdx.x;
  const int lane = tid & 63;
  const int wid = tid >> 6;
  const int wm = wid >> 1, wn = wid & 1;
  const int m0 = blockIdx.y * 128;
  const int n0 = blockIdx.x * 128;
  const int lo = lane & 15, hi = lane >> 4;

  f32x4 acc[4][4];
  #pragma unroll
  for (int i = 0; i < 4; ++i)
    #pragma unroll
    for (int j = 0; j < 4; ++j) acc[i][j] = (f32x4)0.0f;

  const int nk = KDIM / 64;
  for (int ki = 0; ki < nk; ++ki) {
    __syncthreads();
    #pragma unroll
    for (int it = 0; it < 4; ++it) {          // 1024 16B-chunks per tile, 4/thread
      int cid = tid + it * 256;
      int row = cid >> 3, cp = cid & 7;
      int kch = cp ^ (row & 7);
      *(bf16x8*)&As[row * 64 + cp * 8] =
          *(const bf16x8*)&Amat[(size_t)(m0 + row) * KDIM + ki * 64 + kch * 8];
      *(bf16x8*)&Bs[row * 64 + cp * 8] =
          *(const bf16x8*)&Bmat[(size_t)(n0 + row) * KDIM + ki * 64 + kch * 8];
    }
    __syncthreads();
    #pragma unroll
    for (int kc = 0; kc < 2; ++kc) {
      bf16x8 af[4], bfr[4];
      #pragma unroll
      for (int fm = 0; fm < 4; ++fm) {
        int row = wm * 64 + fm * 16 + lo;
        int ch = (kc * 4 + hi) ^ (row & 7);
        af[fm] = *(bf16x8*)&As[row * 64 + ch * 8];
      }
      #pragma unroll
      for (int fn = 0; fn < 4; ++fn) {
        int row = wn * 64 + fn * 16 + lo;
        int ch = (kc * 4 + hi) ^ (row & 7);
        bfr[fn] = *(bf16x8*)&Bs[row * 64 + ch * 8];
      }
      #pragma unroll
      for (int fm = 0; fm < 4; ++fm)
        #pragma unroll
        for (int fn = 0; fn < 4; ++fn)
          acc[fm][fn] = MFMA16(af[fm], bfr[fn], acc[fm][fn]);
    }
  }

  #pragma unroll
  for (int fm = 0; fm < 4; ++fm) {
    int r0 = m0 + wm * 64 + fm * 16 + hi * 4;
    #pragma unroll
    for (int fn = 0; fn < 4; ++fn) {
      int w = n0 + wn * 64 + fn * 16 + lo;
      if constexpr (EPI == 0) {
        int idx = char_idx[w * NC + tstep];
        float4 pe = *(const float4*)&PEb[(size_t)idx * MC + r0];
        float gi = acc[fm][fn][0] + pe.x;
        float gf = acc[fm][fn][1] + pe.y;
        float gg = acc[fm][fn][2] + pe.z;
        float go = acc[fm][fn][3] + pe.w;
        int j = r0 >> 2;
        float c = sigf(gf) * c_state[(size_t)w * NE + j] + sigf(gi) * tanh_f(gg);
        c_state[(size_t)w * NE + j] = c;
        h_out[(size_t)w * NE + j] = f2bf(sigf(go) * tanh_f(c));
      } else {
        float4 bb = *(const float4*)&bias[r0];
        bf16x4 o;
        o[0] = f2bf(acc[fm][fn][0] + bb.x);
        o[1] = f2bf(acc[fm][fn][1] + bb.y);
        o[2] = f2bf(acc[fm][fn][2] + bb.z);
        o[3] = f2bf(acc[fm][fn][3] + bb.w);
        *(bf16x4*)&pw_out[(size_t)w * RW + r0] = o;
      }
    }
  }
}

// ===================== build Xw = [word_emb(gather) ; char_feat] bf16, row w' = s*32+b =====================
__global__ __launch_bounds__(64) void k_xw(
    const int* __restrict__ word_idx, const float* __restrict__ word_emb,
    const short* __restrict__ h_char, short* __restrict__ Xw)
{
  int wp = blockIdx.x;             // w' = s*B + b
  int s = wp >> 5, b = wp & 31;
  int w = b * NS + s;              // char/word index order
  int tid = threadIdx.x;
  int widx = word_idx[w];
  #pragma unroll
  for (int g = 0; g < 2; ++g) {
    int k4 = (tid + g * 64) * 4;
    bf16x4 o;
    if (k4 < NE) {
      float4 v = *(const float4*)&word_emb[(size_t)widx * NE + k4];
      o[0] = f2bf(v.x); o[1] = f2bf(v.y); o[2] = f2bf(v.z); o[3] = f2bf(v.w);
    } else {
      o = *(const bf16x4*)&h_char[(size_t)w * NE + (k4 - NE)];
    }
    *(bf16x4*)&Xw[(size_t)wp * KW + k4] = o;
  }
}

// ===================== persistent word LSTM v13: serial-chain trimming =====================
// v12 falsified the A-refetch theory (VGPR=64 unchanged, time unchanged -> weights were in
// AGPRs all along). Honest budget of the 7500cy step: LDS B-broadcast ~1700 (BW floor for
// 128 ds_read_b128/CU), exchange RTs ~1200, HBM drain entanglement ~600-900 (poll round-1
// vmcnt(0) waits for loop-bottom PW prefetch + word_hs store: in-order vmcnt retirement),
// publish drain ~300, 2 barriers ~200, compute ~600, poll quantization+skew ~1000.
// v13 trims three verified chain links, protocol otherwise byte-identical:
//  1) publish reorder: h-stores -> vmcnt(0) [h only] -> flag; word_hs+PW issued AFTER the
//     flag so their ~900cy retires inside the next poll spin, not between cell and flag.
//  2) 2nd barrier -> LDS monotonic arrive counter (ds_add_rtn): last wave stores the block
//     flag; early waves run ahead into the next poll. Parity safety: write of parity P at
//     s+2 is gated by flag(s+2) <= every wave's arrive(s+1) <= their reads of P at s.
//  3) FAST hot spin (1 block/CU: spinning steals nothing) + per-lane global_store_short
//     publish (drops the shfl_xor pack).
template<bool FAST>
__device__ __forceinline__ void word_loop(
    const short* __restrict__ Whh, const short* __restrict__ PW,
    short* hdat, uint32_t* flags, short* __restrict__ word_hs,
    short* h_lds, uint32_t* arr, int bk, int tid)
{
  const int lane = tid & 63, wv = tid >> 6;
  const int lo = lane & 15, hi = lane >> 4;
  const int wr = wv >> 1, wc = wv & 1;
  const int rowbase = bk * 64 + wr * 16;   // 16 gate rows for this wave
  const int b = wc * 16 + lo;              // batch column
  const int jl = (rowbase >> 2) + hi;      // this lane's j
  const int r4 = rowbase + hi * 4;         // gate-group base row

  // resident weights: rows rowbase..rowbase+15, full K=512 (16 frags, AGPR-backed)
  bf16x8 a[16];
  #pragma unroll
  for (int kc = 0; kc < 16; ++kc)
    a[kc] = *(const bf16x8*)&Whh[(size_t)(rowbase + lo) * NH + kc * 32 + hi * 8];

  // consumer data slice: batch db, shorts {dlo + k*128 .. +8} for k=0..3
  const int db = tid >> 4, dlo = (tid & 15) * 8;
  const short* dA = hdat + db * 512 + dlo;        // slot 0
  const short* dB = dA + 16384;                   // slot 1
  const uint32_t* fA = flags + (lane & 31);       // slot 0: 32 flags in 2 lines
  const uint32_t* fB = fA + 64;                   // slot 1 (256B stride, own lines)

  float cst = 0.0f;
  bf16x4 pw  = *(const bf16x4*)&PW[(size_t)(0 * NB + b) * RW + r4];
  bf16x4 pw1 = *(const bf16x4*)&PW[(size_t)(1 * NB + b) * RW + r4];

  for (int s = 0; s < NS; ++s) {
    const uint32_t tv = (uint32_t)s;
    const int par = s & 1;

    // ---- per-block flag poll: 1 dword/lane, 2 line-req/wave/round ----
    // Round 1's vmcnt(0) also drains last iteration's word_hs store + PW prefetch;
    // their HBM latency overlaps the genuine wait for other blocks' flags.
    {
      const uint32_t* fp = par ? fB : fA;
      int tries = 0;
      for (;;) {
        uint32_t f;
        if constexpr (FAST)
          asm volatile("global_load_dword %0, %1, off sc0\n\t"
                       "s_waitcnt vmcnt(0)" : "=&v"(f) : "v"(fp));
        else
          asm volatile("global_load_dword %0, %1, off sc1\n\t"
                       "s_waitcnt vmcnt(0)" : "=&v"(f) : "v"(fp));
        if (__ballot(f == tv) == ~0ull) break;
        if constexpr (!FAST) {
          if (++tries > 768) {   // liveness net (same scope as protocol)
            if (__ballot(agent_ld(fp) == tv) == ~0ull) break;
            tries = 0;
          }
          __builtin_amdgcn_s_sleep(1);
        }
        // FAST: hot spin -- 1 block/CU, nothing to yield to
      }
    }

    // ---- one-shot dense data load: per wave-instr 4x256B contiguous chunks ----
    const short* sp = par ? dB : dA;
    bf16x8 d0, d1, d2, d3;
    if constexpr (FAST)
      asm volatile("global_load_dwordx4 %0, %4, off sc0\n\t"
                   "global_load_dwordx4 %1, %4, off offset:256 sc0\n\t"
                   "global_load_dwordx4 %2, %4, off offset:512 sc0\n\t"
                   "global_load_dwordx4 %3, %4, off offset:768 sc0\n\t"
                   "s_waitcnt vmcnt(0)"
                   : "=&v"(d0), "=&v"(d1), "=&v"(d2), "=&v"(d3) : "v"(sp));
    else
      asm volatile("global_load_dwordx4 %0, %4, off sc1\n\t"
                   "global_load_dwordx4 %1, %4, off offset:256 sc1\n\t"
                   "global_load_dwordx4 %2, %4, off offset:512 sc1\n\t"
                   "global_load_dwordx4 %3, %4, off offset:768 sc1\n\t"
                   "s_waitcnt vmcnt(0)"
                   : "=&v"(d0), "=&v"(d1), "=&v"(d2), "=&v"(d3) : "v"(sp));

    short* buf = h_lds + par * (32 * 520);
    short* dst = buf + db * 520 + dlo;
    *(bf16x8*)&dst[0]   = d0;
    *(bf16x8*)&dst[128] = d1;
    *(bf16x8*)&dst[256] = d2;
    *(bf16x8*)&dst[384] = d3;
    __syncthreads();

    // ---- gates = PW + Whh @ h : 16 MFMAs in four independent dep-chains ----
    f32x4 acc0, acc1, acc2, acc3;
    #pragma unroll
    for (int q = 0; q < 4; ++q) {
      acc0[q] = bf2f(pw[q]); acc1[q] = 0.0f; acc2[q] = 0.0f; acc3[q] = 0.0f;
    }
    #pragma unroll
    for (int kc = 0; kc < 16; kc += 4) {
      bf16x8 h0 = *(bf16x8*)((const char*)buf + b * 1040 + (kc + 0) * 64 + hi * 16);
      bf16x8 h1 = *(bf16x8*)((const char*)buf + b * 1040 + (kc + 1) * 64 + hi * 16);
      bf16x8 h2 = *(bf16x8*)((const char*)buf + b * 1040 + (kc + 2) * 64 + hi * 16);
      bf16x8 h3 = *(bf16x8*)((const char*)buf + b * 1040 + (kc + 3) * 64 + hi * 16);
      acc0 = MFMA16(a[kc + 0], h0, acc0);
      acc1 = MFMA16(a[kc + 1], h1, acc1);
      acc2 = MFMA16(a[kc + 2], h2, acc2);
      acc3 = MFMA16(a[kc + 3], h3, acc3);
    }
    f32x4 acc;
    #pragma unroll
    for (int q = 0; q < 4; ++q) acc[q] = (acc0[q] + acc1[q]) + (acc2[q] + acc3[q]);

    // ---- cell (1 j per lane) ----
    float c = sigf(acc[1]) * cst + sigf(acc[0]) * tanh_f(acc[2]);
    cst = c;
    short hv = f2bf(sigf(acc[3]) * tanh_f(c));

    // ---- publish h(s+1): per-lane short store; minimal drain; arrive-counter flag ----
    const int npar = (s + 1) & 1;
    {
      short* hp = hdat + (npar << 14) + b * 512 + jl;
      if constexpr (FAST)
        asm volatile("global_store_short %0, %1, off sc0" :: "v"(hp), "v"((uint32_t)(uint16_t)hv) : "memory");
      else
        asm volatile("global_store_short %0, %1, off sc1" :: "v"(hp), "v"((uint32_t)(uint16_t)hv) : "memory");
    }
    asm volatile("s_waitcnt vmcnt(0)" ::: "memory");  // drains ONLY h-stores (~300cy)
    // per-block arrive: monotonic LDS counter replaces the 2nd barrier
    if (lane == 0) {
      uint32_t old = __hip_atomic_fetch_add(&arr[npar], 1u, __ATOMIC_RELAXED,
                                            __HIP_MEMORY_SCOPE_WORKGROUP);
      if ((old & 7u) == 7u) {                         // last of 8 waves this step
        uint32_t* fq = flags + npar * 64 + bk;
        if constexpr (FAST)
          asm volatile("global_store_dword %0, %1, off sc0"
                       :: "v"(fq), "v"((uint32_t)(s + 1)) : "memory");
        else
          asm volatile("global_store_dword %0, %1, off sc1"
                       :: "v"(fq), "v"((uint32_t)(s + 1)) : "memory");
      }
    }

    // ---- off-critical-path HBM ops: retire inside the next poll spin ----
    word_hs[((size_t)b * NS + s) * NH + jl] = hv;
    int s2 = (s + 2 < NS) ? (s + 2) : (NS - 1);
    bf16x4 pw2 = *(const bf16x4*)&PW[(size_t)(s2 * NB + b) * RW + r4];
    pw = pw1; pw1 = pw2;
  }
}

__global__ __launch_bounds__(512, 1) void k_word(
    const short* __restrict__ Whh,          // [2048][512] bf16 gate-interleaved
    const short* __restrict__ PW,           // [S][B][2048] bf16 (pre-act + bias)
    uint8_t* __restrict__ xb,               // hdat 64K | flags 512B | control
    short* __restrict__ word_hs)            // [B][S][512] bf16
{
  __shared__ __align__(16) short h_lds[2 * 32 * 520];   // 2 x 33280 B
  __shared__ uint32_t arr_cnt[2];
  __shared__ int sh_bk, sh_fast;
  const int tid = threadIdx.x;

  short*    hdat  = (short*)xb;                   // [2][32][512] bf16
  uint32_t* flags = (uint32_t*)(xb + 65536);      // [2][64] u32 (32 used/slot, 2 lines)
  uint32_t* cnt   = (uint32_t*)(xb + 66048);      // [8] election bins
  uint32_t* win   = (uint32_t*)(xb + 66080);
  uint32_t* probe = (uint32_t*)(xb + 66112);      // sc0-tested line
  uint32_t* rdy1  = (uint32_t*)(xb + 66240);      // agent-only lines below
  uint32_t* ack1  = (uint32_t*)(xb + 66368);
  uint32_t* rdy2  = (uint32_t*)(xb + 66496);
  uint32_t* verd  = (uint32_t*)(xb + 66624);

  if (tid < 2) arr_cnt[tid] = 0u;

  // ---- election: deadlock-free even with garbage XCC_ID (pigeonhole over 8 bins) ----
  if (tid == 0) {
    uint32_t xcc;
    asm volatile("s_getreg_b32 %0, hwreg(HW_REG_XCC_ID)" : "=s"(xcc));
    xcc &= 7u;
    uint32_t slot = __hip_atomic_fetch_add(&cnt[xcc], 1u, __ATOMIC_RELAXED,
                                           __HIP_MEMORY_SCOPE_AGENT);
    if (slot == 31u) {
      uint32_t exp = 0u;
      __hip_atomic_compare_exchange_strong(win, &exp, xcc + 1u, __ATOMIC_RELAXED,
                                           __ATOMIC_RELAXED, __HIP_MEMORY_SCOPE_AGENT);
    }
    uint32_t w;
    for (;;) {
      w = agent_ld(win);
      if (w != 0u) break;
      __builtin_amdgcn_s_sleep(8);
    }
    sh_bk = (w == xcc + 1u && slot < 32u) ? (int)slot : -1;
  }
  __syncthreads();
  const int bk = sh_bk;
  if (bk < 0) return;

  // ---- two-round sc0 probe (worker0 stores, worker31 polls same line twice) ----
  if (tid == 0) {
    if (bk == 0) {
      asm volatile("global_store_dword %0, %1, off sc0" :: "v"(probe), "v"(0x11111111u) : "memory");
      asm volatile("s_waitcnt vmcnt(0)" ::: "memory");
      agent_st(rdy1, 1u);
      uint32_t a;
      for (;;) { a = agent_ld(ack1); if (a != 0u) break; __builtin_amdgcn_s_sleep(4); }
      if (a == 1u) {
        asm volatile("global_store_dword %0, %1, off sc0" :: "v"(probe), "v"(0x22222222u) : "memory");
        asm volatile("s_waitcnt vmcnt(0)" ::: "memory");
        agent_st(rdy2, 1u);
      }
    } else if (bk == 31) {
      for (;;) { if (agent_ld(rdy1) != 0u) break; __builtin_amdgcn_s_sleep(4); }
      bool okA = false;
      for (int i = 0; i < 192 && !okA; ++i) {
        uint32_t pv;
        asm volatile("global_load_dword %0, %1, off sc0\n\ts_waitcnt vmcnt(0)"
                     : "=&v"(pv) : "v"(probe));
        okA = (pv == 0x11111111u);
        if (!okA) __builtin_amdgcn_s_sleep(2);
      }
      agent_st(ack1, okA ? 1u : 2u);
      bool okB = false;
      if (okA) {
        for (;;) { if (agent_ld(rdy2) != 0u) break; __builtin_amdgcn_s_sleep(4); }
        for (int i = 0; i < 192 && !okB; ++i) {
          uint32_t pv;
          asm volatile("global_load_dword %0, %1, off sc0\n\ts_waitcnt vmcnt(0)"
                       : "=&v"(pv) : "v"(probe));
          okB = (pv == 0x22222222u);
          if (!okB) __builtin_amdgcn_s_sleep(2);
        }
      }
      agent_st(verd, okB ? 1u : 2u);
    }
    uint32_t v;
    for (;;) { v = agent_ld(verd); if (v != 0u) break; __builtin_amdgcn_s_sleep(4); }
    sh_fast = (v == 1u);
  }
  __syncthreads();

  if (sh_fast)
    word_loop<true >(Whh, PW, hdat, flags, word_hs, h_lds, arr_cnt, bk, tid);
  else
    word_loop<false>(Whh, PW, hdat, flags, word_hs, h_lds, arr_cnt, bk, tid);
}

// ===================== tag projection + log_softmax =====================
__global__ __launch_bounds__(256) void k_tags(
    const short* __restrict__ word_hs, const float* __restrict__ Wt,
    const float* __restrict__ bt, float* __restrict__ out)
{
  __shared__ __align__(16) short Ws[64 * 256];   // 32KB: one K-half
  const int tid = threadIdx.x, lane = tid & 63, wid = tid >> 6;
  const int lo = lane & 15, hi = lane >> 4;
  const int n0 = blockIdx.x * 128;
  const int wb = n0 + wid * 32;

  f32x4 acc[4][2];
  #pragma unroll
  for (int fm = 0; fm < 4; ++fm)
    #pragma unroll
    for (int fn = 0; fn < 2; ++fn) acc[fm][fn] = (f32x4)0.0f;

  for (int half = 0; half < 2; ++half) {
    __syncthreads();
    for (int cid = tid; cid < 2048; cid += 256) {   // 64 rows x 32 chunks
      int row = cid >> 5, cp = cid & 31;
      int kch = cp ^ (row & 7);
      bf16x8 v;
      if (row < NT) {
        const float* src = &Wt[(size_t)row * KW + half * 256 + kch * 8];
        #pragma unroll
        for (int e = 0; e < 8; ++e) v[e] = f2bf(src[e]);
      } else v = (bf16x8)0;
      *(bf16x8*)&Ws[row * 256 + cp * 8] = v;
    }
    __syncthreads();
    #pragma unroll
    for (int kc = 0; kc < 8; ++kc) {
      bf16x8 bfr[2];
      #pragma unroll
      for (int fn = 0; fn < 2; ++fn) {
        int w = wb + fn * 16 + lo;
        bfr[fn] = *(const bf16x8*)&word_hs[(size_t)w * KW + half * 256 + kc * 32 + hi * 8];
      }
      #pragma unroll
      for (int fm = 0; fm < 4; ++fm) {
        int row = fm * 16 + lo;
        int ch = (kc * 4 + hi) ^ (row & 7);
        bf16x8 av = *(bf16x8*)&Ws[row * 256 + ch * 8];
        acc[fm][0] = MFMA16(av, bfr[0], acc[fm][0]);
        acc[fm][1] = MFMA16(av, bfr[1], acc[fm][1]);
      }
    }
  }

  #pragma unroll
  for (int fn = 0; fn < 2; ++fn) {
    int w = wb + fn * 16 + lo;
    float lg[16];
    float m = -1e30f;
    #pragma unroll
    for (int fm = 0; fm < 4; ++fm)
      #pragma unroll
      for (int q = 0; q < 4; ++q) {
        int tg = fm * 16 + hi * 4 + q;
        float bv = (tg < NT) ? bt[tg] : 0.0f;
        float v = acc[fm][fn][q] + bv;
        lg[fm * 4 + q] = v;
        if (tg < NT) m = fmaxf(m, v);
      }
    m = fmaxf(m, __shfl_xor(m, 16));
    m = fmaxf(m, __shfl_xor(m, 32));
    float s = 0.0f;
    #pragma unroll
    for (int fm = 0; fm < 4; ++fm)
      #pragma unroll
      for (int q = 0; q < 4; ++q) {
        int tg = fm * 16 + hi * 4 + q;
        if (tg < NT) s += __expf(lg[fm * 4 + q] - m);
      }
    s += __shfl_xor(s, 16);
    s += __shfl_xor(s, 32);
    float lz = m + __logf(s);
    #pragma unroll
    for (int fm = 0; fm < 4; ++fm)
      #pragma unroll
      for (int q = 0; q < 4; ++q) {
        int tg = fm * 16 + hi * 4 + q;
        if (tg < NT) out[(size_t)w * NT + tg] = lg[fm * 4 + q] - lz;
      }
  }
}

// ===================== launch =====================
extern "C" void kernel_launch(void* const* d_in, const int* in_sizes, int n_in,
                              void* d_out, int out_size, void* d_ws, size_t ws_size,
                              hipStream_t stream) {
  const int*   char_idx = (const int*)  d_in[0];
  const int*   word_idx = (const int*)  d_in[1];
  const float* char_emb = (const float*)d_in[2];
  const float* word_emb = (const float*)d_in[3];
  const float* Wc_ih    = (const float*)d_in[4];
  const float* Wc_hh    = (const float*)d_in[5];
  const float* bc       = (const float*)d_in[6];
  const float* Ww_ih    = (const float*)d_in[7];
  const float* Ww_hh    = (const float*)d_in[8];
  const float* bw       = (const float*)d_in[9];
  const float* Wt       = (const float*)d_in[10];
  const float* bt       = (const float*)d_in[11];
  float* out = (float*)d_out;

  const size_t MB = 1ull << 20;
  uint8_t* w8 = (uint8_t*)d_ws;
  float* PEb   = (float*)(w8 + 0);                 // 512K
  short* WhhC  = (short*)(w8 + 512 * 1024);        // 512K
  short* WihW  = (short*)(w8 + 1 * MB);            // 2M
  short* WhhW  = (short*)(w8 + 3 * MB);            // 2M
  float* bwI   = (float*)(w8 + 5 * MB);            // 8K
  uint8_t* xb  = (uint8_t*)(w8 + 5 * MB + 64 * 1024);  // 64K hdat + flags + control
  short* hA    = (short*)(w8 + 6 * MB);            // 16M
  short* hB    = (short*)(w8 + 22 * MB);           // 16M
  short* whs   = (short*)(w8 + 6 * MB);            // 32M (reuses hA/hB after k_xw)
  float* cC    = (float*)(w8 + 38 * MB);           // 32M
  short* Xw    = (short*)(w8 + 38 * MB);           // 32M (reuses cC after char steps)
  short* PW    = (short*)(w8 + 70 * MB);           // 128M

  k_prep_pe<<<128, 256, 0, stream>>>(char_emb, Wc_ih, bc, PEb);
  k_prep_w<<<2048, 256, 0, stream>>>(Wc_hh, Ww_ih, Ww_hh, bw, WhhC, WihW, WhhW, bwI);

  // char LSTM
  k_char0<<<NWRD, 256, 0, stream>>>(char_idx, PEb, cC, hA);
  for (int t = 1; t < NC; ++t) {
    short* src = (t & 1) ? hA : hB;
    short* dst = (t & 1) ? hB : hA;
    gemm_epi<256, 0><<<dim3(256, 8), 256, 0, stream>>>(
        WhhC, src, PEb, char_idx, t, cC, dst, nullptr, nullptr);
  }
  // h_12 ends in hB

  // word LSTM input projections for all timesteps
  k_xw<<<NWRD, 64, 0, stream>>>(word_idx, word_emb, hB, Xw);
  gemm_epi<512, 1><<<dim3(256, 16), 256, 0, stream>>>(
      WihW, Xw, nullptr, nullptr, 0, nullptr, nullptr, bwI, PW);

  // persistent recurrence: zero hdat slot0 (h_0=0), flags, election+probe control
  hipMemsetAsync(xb, 0, 67584, stream);
  k_word<<<256, 512, 0, stream>>>(WhhW, PW, xb, whs);

  // tags + log_softmax
  k_tags<<<256, 256, 0, stream>>>(whs, Wt, bt, out);
}

// Round 8
// 3962.415 us; speedup vs baseline: 1.4078x; 1.4078x over previous
//
#include <hip/hip_runtime.h>
#include <stdint.h>
#include <stddef.h>

// ===================== problem constants =====================
// B=32 S=1024 C=12 E=256 H=512 V=50000 CS=128 T=50
#define NB   32
#define NS   1024
#define NC   12
#define NE   256
#define NH   512
#define NT   50
#define NWRD 32768          // B*S
#define MC   1024           // 4*E  (char gate rows)
#define RW   2048           // 4*H  (word gate rows)
#define KW   512            // 2*E

// ===================== types / helpers =====================
typedef short bf16x8 __attribute__((ext_vector_type(8)));
typedef short bf16x4 __attribute__((ext_vector_type(4)));
typedef float f32x4  __attribute__((ext_vector_type(4)));
typedef unsigned int u32x4 __attribute__((ext_vector_type(4)));

#define MFMA16(a,b,c) __builtin_amdgcn_mfma_f32_16x16x32_bf16(a, b, c, 0, 0, 0)

__device__ __forceinline__ float bf2f(short u){
  return __uint_as_float(((uint32_t)(uint16_t)u) << 16);
}
__device__ __forceinline__ short f2bf(float f){
  uint32_t u = __float_as_uint(f);
  uint32_t r = (u + 0x7FFFu + ((u >> 16) & 1u)) >> 16;  // RNE
  return (short)r;
}
__device__ __forceinline__ float sigf(float x){
  float e = __expf(-fabsf(x));
  float s = 1.0f / (1.0f + e);
  return x >= 0.0f ? s : 1.0f - s;
}
__device__ __forceinline__ float tanh_f(float x){
  float e = __expf(-2.0f * fabsf(x));
  float r = (1.0f - e) / (1.0f + e);
  return x >= 0.0f ? r : -r;
}
__device__ __forceinline__ uint32_t agent_ld(const uint32_t* p){
  return __hip_atomic_load(p, __ATOMIC_RELAXED, __HIP_MEMORY_SCOPE_AGENT);
}
__device__ __forceinline__ void agent_st(uint32_t* p, uint32_t v){
  __hip_atomic_store(p, v, __ATOMIC_RELAXED, __HIP_MEMORY_SCOPE_AGENT);
}

// ===================== prep: PEb = char_emb @ Wc_ih^T + bc (gate-interleaved) =====================
__global__ __launch_bounds__(256) void k_prep_pe(
    const float* __restrict__ char_emb, const float* __restrict__ Wc_ih,
    const float* __restrict__ bc, float* __restrict__ PEb)
{
  __shared__ float ce[NE];
  int a = blockIdx.x, tid = threadIdx.x;
  ce[tid] = char_emb[a * NE + tid];
  __syncthreads();
  int j = tid;
  float acc[4];
  #pragma unroll
  for (int g = 0; g < 4; ++g) acc[g] = 0.0f;
  for (int k = 0; k < NE; ++k) {
    float c = ce[k];
    #pragma unroll
    for (int g = 0; g < 4; ++g)
      acc[g] += c * Wc_ih[(size_t)(g * NE + j) * NE + k];
  }
  float4 o;
  o.x = acc[0] + bc[0 * NE + j];
  o.y = acc[1] + bc[1 * NE + j];
  o.z = acc[2] + bc[2 * NE + j];
  o.w = acc[3] + bc[3 * NE + j];
  *(float4*)&PEb[(size_t)a * MC + j * 4] = o;
}

// ===================== prep: weight convert + gate-interleave =====================
__global__ __launch_bounds__(256) void k_prep_w(
    const float* __restrict__ Wc_hh, const float* __restrict__ Ww_ih,
    const float* __restrict__ Ww_hh, const float* __restrict__ bw,
    short* __restrict__ WhhC, short* __restrict__ WihW,
    short* __restrict__ WhhW, float* __restrict__ bwI)
{
  int r = blockIdx.x;            // 0..2047
  int j = r >> 2, g = r & 3, tid = threadIdx.x;
  if (r < MC) {                  // char Whh: [1024][256]
    float v = Wc_hh[(size_t)(g * NE + j) * NE + tid];
    WhhC[(size_t)r * NE + tid] = f2bf(v);
  }
  #pragma unroll
  for (int kk = 0; kk < 2; ++kk) {
    int k = tid + kk * 256;
    WihW[(size_t)r * KW + k] = f2bf(Ww_ih[(size_t)(g * NH + j) * KW + k]);
    WhhW[(size_t)r * NH + k] = f2bf(Ww_hh[(size_t)(g * NH + j) * NH + k]);
  }
  if (tid == 0) bwI[r] = bw[g * NH + j];
}

// ===================== char step 0 (h=c=0): pure gather + cell =====================
__global__ __launch_bounds__(256) void k_char0(
    const int* __restrict__ char_idx, const float* __restrict__ PEb,
    float* __restrict__ c_state, short* __restrict__ h_out)
{
  int w = blockIdx.x, j = threadIdx.x;
  int idx = char_idx[w * NC + 0];
  float4 pe = *(const float4*)&PEb[(size_t)idx * MC + j * 4];
  float c = sigf(pe.x) * tanh_f(pe.z);          // sig(i)*tanh(g), c_prev=0
  float h = sigf(pe.w) * tanh_f(c);             // sig(o)*tanh(c)
  c_state[(size_t)w * NE + j] = c;
  h_out[(size_t)w * NE + j] = f2bf(h);
}

// ===================== generic MFMA GEMM: D[r][n] = A[r][:]·B[n][:], fused epilogue =====================
template<int KDIM, int EPI>
__global__ __launch_bounds__(256) void gemm_epi(
    const short* __restrict__ Amat, const short* __restrict__ Bmat,
    const float* __restrict__ PEb, const int* __restrict__ char_idx, int tstep,
    float* __restrict__ c_state, short* __restrict__ h_out,
    const float* __restrict__ bias, short* __restrict__ pw_out)
{
  __shared__ __align__(16) short As[128 * 64];
  __shared__ __align__(16) short Bs[128 * 64];
  const int tid = threadIdx.x;
  const int lane = tid & 63;
  const int wid = tid >> 6;
  const int wm = wid >> 1, wn = wid & 1;
  const int m0 = blockIdx.y * 128;
  const int n0 = blockIdx.x * 128;
  const int lo = lane & 15, hi = lane >> 4;

  f32x4 acc[4][4];
  #pragma unroll
  for (int i = 0; i < 4; ++i)
    #pragma unroll
    for (int j = 0; j < 4; ++j) acc[i][j] = (f32x4)0.0f;

  const int nk = KDIM / 64;
  for (int ki = 0; ki < nk; ++ki) {
    __syncthreads();
    #pragma unroll
    for (int it = 0; it < 4; ++it) {          // 1024 16B-chunks per tile, 4/thread
      int cid = tid + it * 256;
      int row = cid >> 3, cp = cid & 7;
      int kch = cp ^ (row & 7);
      *(bf16x8*)&As[row * 64 + cp * 8] =
          *(const bf16x8*)&Amat[(size_t)(m0 + row) * KDIM + ki * 64 + kch * 8];
      *(bf16x8*)&Bs[row * 64 + cp * 8] =
          *(const bf16x8*)&Bmat[(size_t)(n0 + row) * KDIM + ki * 64 + kch * 8];
    }
    __syncthreads();
    #pragma unroll
    for (int kc = 0; kc < 2; ++kc) {
      bf16x8 af[4], bfr[4];
      #pragma unroll
      for (int fm = 0; fm < 4; ++fm) {
        int row = wm * 64 + fm * 16 + lo;
        int ch = (kc * 4 + hi) ^ (row & 7);
        af[fm] = *(bf16x8*)&As[row * 64 + ch * 8];
      }
      #pragma unroll
      for (int fn = 0; fn < 4; ++fn) {
        int row = wn * 64 + fn * 16 + lo;
        int ch = (kc * 4 + hi) ^ (row & 7);
        bfr[fn] = *(bf16x8*)&Bs[row * 64 + ch * 8];
      }
      #pragma unroll
      for (int fm = 0; fm < 4; ++fm)
        #pragma unroll
        for (int fn = 0; fn < 4; ++fn)
          acc[fm][fn] = MFMA16(af[fm], bfr[fn], acc[fm][fn]);
    }
  }

  #pragma unroll
  for (int fm = 0; fm < 4; ++fm) {
    int r0 = m0 + wm * 64 + fm * 16 + hi * 4;
    #pragma unroll
    for (int fn = 0; fn < 4; ++fn) {
      int w = n0 + wn * 64 + fn * 16 + lo;
      if constexpr (EPI == 0) {
        int idx = char_idx[w * NC + tstep];
        float4 pe = *(const float4*)&PEb[(size_t)idx * MC + r0];
        float gi = acc[fm][fn][0] + pe.x;
        float gf = acc[fm][fn][1] + pe.y;
        float gg = acc[fm][fn][2] + pe.z;
        float go = acc[fm][fn][3] + pe.w;
        int j = r0 >> 2;
        float c = sigf(gf) * c_state[(size_t)w * NE + j] + sigf(gi) * tanh_f(gg);
        c_state[(size_t)w * NE + j] = c;
        h_out[(size_t)w * NE + j] = f2bf(sigf(go) * tanh_f(c));
      } else {
        float4 bb = *(const float4*)&bias[r0];
        bf16x4 o;
        o[0] = f2bf(acc[fm][fn][0] + bb.x);
        o[1] = f2bf(acc[fm][fn][1] + bb.y);
        o[2] = f2bf(acc[fm][fn][2] + bb.z);
        o[3] = f2bf(acc[fm][fn][3] + bb.w);
        *(bf16x4*)&pw_out[(size_t)w * RW + r0] = o;
      }
    }
  }
}

// ===================== build Xw = [word_emb(gather) ; char_feat] bf16, row w' = s*32+b =====================
__global__ __launch_bounds__(64) void k_xw(
    const int* __restrict__ word_idx, const float* __restrict__ word_emb,
    const short* __restrict__ h_char, short* __restrict__ Xw)
{
  int wp = blockIdx.x;             // w' = s*B + b
  int s = wp >> 5, b = wp & 31;
  int w = b * NS + s;              // char/word index order
  int tid = threadIdx.x;
  int widx = word_idx[w];
  #pragma unroll
  for (int g = 0; g < 2; ++g) {
    int k4 = (tid + g * 64) * 4;
    bf16x4 o;
    if (k4 < NE) {
      float4 v = *(const float4*)&word_emb[(size_t)widx * NE + k4];
      o[0] = f2bf(v.x); o[1] = f2bf(v.y); o[2] = f2bf(v.z); o[3] = f2bf(v.w);
    } else {
      o = *(const bf16x4*)&h_char[(size_t)w * NE + (k4 - NE)];
    }
    *(bf16x4*)&Xw[(size_t)wp * KW + k4] = o;
  }
}

// ===================== persistent word LSTM v14: v11 + PW-drain disentanglement =====================
// v13 bundled 3 changes and regressed (short-store partial-sector RMW + hot-spin poll
// congestion). v14 reverts to the best structure (v11, k_word=3160us) and applies the ONE
// surviving insight: stores ack at L2 (~300cy) but the PW PREFETCH (HBM load, ~800-900cy)
// was issued at loop bottom, ~100cy before the next poll's vmcnt(0) full-drain -> in-order
// vmcnt retirement puts ~800cy HBM latency on the straggler's poll chain every step.
// Fix: issue PW(s+2) right after the data-load vmcnt(0). It then has LDS-stage + barrier
// + MFMA + cell (~800cy) head start; the publish vmcnt(0) absorbs its residual (~100cy),
// and poll round-1 drains only the word_hs store (~300cy L2 ack).
template<bool FAST>
__device__ __forceinline__ void word_loop(
    const short* __restrict__ Whh, const short* __restrict__ PW,
    short* hdat, uint32_t* flags, short* __restrict__ word_hs,
    short* h_lds, int bk, int tid)
{
  const int lane = tid & 63, wv = tid >> 6;
  const int lo = lane & 15, hi = lane >> 4;
  const int wr = wv >> 1, wc = wv & 1;
  const int rowbase = bk * 64 + wr * 16;   // 16 gate rows for this wave
  const int b = wc * 16 + lo;              // batch column
  const int jl = (rowbase >> 2) + hi;      // this lane's j
  const int r4 = rowbase + hi * 4;         // gate-group base row

  // resident weights: rows rowbase..rowbase+15, full K=512 (16 frags, AGPR-backed)
  bf16x8 a[16];
  #pragma unroll
  for (int kc = 0; kc < 16; ++kc)
    a[kc] = *(const bf16x8*)&Whh[(size_t)(rowbase + lo) * NH + kc * 32 + hi * 8];

  // consumer data slice: batch db, shorts {dlo + k*128 .. +8} for k=0..3
  const int db = tid >> 4, dlo = (tid & 15) * 8;
  const short* dA = hdat + db * 512 + dlo;        // slot 0
  const short* dB = dA + 16384;                   // slot 1
  const uint32_t* fA = flags + (lane & 31);       // slot 0: 32 flags in 2 lines
  const uint32_t* fB = fA + 64;                   // slot 1 (256B stride, own lines)

  float cst = 0.0f;
  bf16x4 pw  = *(const bf16x4*)&PW[(size_t)(0 * NB + b) * RW + r4];
  bf16x4 pw1 = *(const bf16x4*)&PW[(size_t)(1 * NB + b) * RW + r4];

  for (int s = 0; s < NS; ++s) {
    const uint32_t tv = (uint32_t)s;
    const int par = s & 1;

    // ---- per-block flag poll: 1 dword/lane, 2 line-req/wave/round ----
    // Round 1's vmcnt(0) drains only the word_hs store (L2 ack ~300cy); PW was
    // issued mid-iteration and already retired at the publish drain.
    {
      const uint32_t* fp = par ? fB : fA;
      int tries = 0;
      for (;;) {
        uint32_t f;
        if constexpr (FAST)
          asm volatile("global_load_dword %0, %1, off sc0\n\t"
                       "s_waitcnt vmcnt(0)" : "=&v"(f) : "v"(fp));
        else
          asm volatile("global_load_dword %0, %1, off sc1\n\t"
                       "s_waitcnt vmcnt(0)" : "=&v"(f) : "v"(fp));
        if (__ballot(f == tv) == ~0ull) break;
        if constexpr (!FAST) {
          if (++tries > 768) {   // liveness net (same scope as protocol)
            if (__ballot(agent_ld(fp) == tv) == ~0ull) break;
            tries = 0;
          }
        }
        __builtin_amdgcn_s_sleep(1);
      }
    }

    // ---- one-shot dense data load: per wave-instr 4x256B contiguous chunks ----
    const short* sp = par ? dB : dA;
    bf16x8 d0, d1, d2, d3;
    if constexpr (FAST)
      asm volatile("global_load_dwordx4 %0, %4, off sc0\n\t"
                   "global_load_dwordx4 %1, %4, off offset:256 sc0\n\t"
                   "global_load_dwordx4 %2, %4, off offset:512 sc0\n\t"
                   "global_load_dwordx4 %3, %4, off offset:768 sc0\n\t"
                   "s_waitcnt vmcnt(0)"
                   : "=&v"(d0), "=&v"(d1), "=&v"(d2), "=&v"(d3) : "v"(sp));
    else
      asm volatile("global_load_dwordx4 %0, %4, off sc1\n\t"
                   "global_load_dwordx4 %1, %4, off offset:256 sc1\n\t"
                   "global_load_dwordx4 %2, %4, off offset:512 sc1\n\t"
                   "global_load_dwordx4 %3, %4, off offset:768 sc1\n\t"
                   "s_waitcnt vmcnt(0)"
                   : "=&v"(d0), "=&v"(d1), "=&v"(d2), "=&v"(d3) : "v"(sp));

    // ---- PW prefetch for s+2, issued HERE (post-detect, post-data-drain): ~800cy of
    // LDS-stage+barrier+MFMA+cell head start before the publish vmcnt(0) absorbs it ----
    int s2 = (s + 2 < NS) ? (s + 2) : (NS - 1);
    bf16x4 pw2 = *(const bf16x4*)&PW[(size_t)(s2 * NB + b) * RW + r4];

    short* buf = h_lds + par * (32 * 520);
    short* dst = buf + db * 520 + dlo;
    *(bf16x8*)&dst[0]   = d0;
    *(bf16x8*)&dst[128] = d1;
    *(bf16x8*)&dst[256] = d2;
    *(bf16x8*)&dst[384] = d3;
    __syncthreads();

    // ---- gates = PW + Whh @ h : 16 MFMAs in four independent dep-chains ----
    f32x4 acc0, acc1, acc2, acc3;
    #pragma unroll
    for (int q = 0; q < 4; ++q) {
      acc0[q] = bf2f(pw[q]); acc1[q] = 0.0f; acc2[q] = 0.0f; acc3[q] = 0.0f;
    }
    #pragma unroll
    for (int kc = 0; kc < 16; kc += 4) {
      bf16x8 h0 = *(bf16x8*)((const char*)buf + b * 1040 + (kc + 0) * 64 + hi * 16);
      bf16x8 h1 = *(bf16x8*)((const char*)buf + b * 1040 + (kc + 1) * 64 + hi * 16);
      bf16x8 h2 = *(bf16x8*)((const char*)buf + b * 1040 + (kc + 2) * 64 + hi * 16);
      bf16x8 h3 = *(bf16x8*)((const char*)buf + b * 1040 + (kc + 3) * 64 + hi * 16);
      acc0 = MFMA16(a[kc + 0], h0, acc0);
      acc1 = MFMA16(a[kc + 1], h1, acc1);
      acc2 = MFMA16(a[kc + 2], h2, acc2);
      acc3 = MFMA16(a[kc + 3], h3, acc3);
    }
    f32x4 acc;
    #pragma unroll
    for (int q = 0; q < 4; ++q) acc[q] = (acc0[q] + acc1[q]) + (acc2[q] + acc3[q]);

    // ---- cell (1 j per lane) ----
    float c = sigf(acc[1]) * cst + sigf(acc[0]) * tanh_f(acc[2]);
    cst = c;
    short hv = f2bf(sigf(acc[3]) * tanh_f(c));

    // ---- publish h(s+1): pair-pack via shfl_xor(16); scope-matched stores ----
    unsigned int own = (unsigned int)(unsigned short)hv;
    unsigned int part = (unsigned int)__shfl_xor((int)own, 16);
    const int npar = (s + 1) & 1;
    if ((hi & 1) == 0) {
      unsigned int val = own | (part << 16);          // mem: [jl]=own, [jl+1]=part
      short* hp = hdat + (npar << 14) + b * 512 + jl;
      if constexpr (FAST)
        asm volatile("global_store_dword %0, %1, off sc0" :: "v"(hp), "v"(val) : "memory");
      else
        asm volatile("global_store_dword %0, %1, off sc1" :: "v"(hp), "v"(val) : "memory");
    }
    asm volatile("s_waitcnt vmcnt(0)" ::: "memory");  // h-stores (~300) + PW residual (~100)
    __syncthreads();                                  // all waves of block drained
    if (tid == 0) {
      uint32_t* fq = flags + npar * 64 + bk;
      if constexpr (FAST)
        asm volatile("global_store_dword %0, %1, off sc0"
                     :: "v"(fq), "v"((uint32_t)(s + 1)) : "memory");
      else
        asm volatile("global_store_dword %0, %1, off sc1"
                     :: "v"(fq), "v"((uint32_t)(s + 1)) : "memory");
    }
    word_hs[((size_t)b * NS + s) * NH + jl] = hv;     // L2-ack'd in next poll round-1
    pw = pw1; pw1 = pw2;
  }
}

__global__ __launch_bounds__(512, 2) void k_word(
    const short* __restrict__ Whh,          // [2048][512] bf16 gate-interleaved
    const short* __restrict__ PW,           // [S][B][2048] bf16 (pre-act + bias)
    uint8_t* __restrict__ xb,               // hdat 64K | flags 512B | control
    short* __restrict__ word_hs)            // [B][S][512] bf16
{
  __shared__ __align__(16) short h_lds[2 * 32 * 520];   // 2 x 33280 B
  __shared__ int sh_bk, sh_fast;
  const int tid = threadIdx.x;

  short*    hdat  = (short*)xb;                   // [2][32][512] bf16
  uint32_t* flags = (uint32_t*)(xb + 65536);      // [2][64] u32 (32 used/slot, 2 lines)
  uint32_t* cnt   = (uint32_t*)(xb + 66048);      // [8] election bins
  uint32_t* win   = (uint32_t*)(xb + 66080);
  uint32_t* probe = (uint32_t*)(xb + 66112);      // sc0-tested line
  uint32_t* rdy1  = (uint32_t*)(xb + 66240);      // agent-only lines below
  uint32_t* ack1  = (uint32_t*)(xb + 66368);
  uint32_t* rdy2  = (uint32_t*)(xb + 66496);
  uint32_t* verd  = (uint32_t*)(xb + 66624);

  // ---- election: deadlock-free even with garbage XCC_ID (pigeonhole over 8 bins) ----
  if (tid == 0) {
    uint32_t xcc;
    asm volatile("s_getreg_b32 %0, hwreg(HW_REG_XCC_ID)" : "=s"(xcc));
    xcc &= 7u;
    uint32_t slot = __hip_atomic_fetch_add(&cnt[xcc], 1u, __ATOMIC_RELAXED,
                                           __HIP_MEMORY_SCOPE_AGENT);
    if (slot == 31u) {
      uint32_t exp = 0u;
      __hip_atomic_compare_exchange_strong(win, &exp, xcc + 1u, __ATOMIC_RELAXED,
                                           __ATOMIC_RELAXED, __HIP_MEMORY_SCOPE_AGENT);
    }
    uint32_t w;
    for (;;) {
      w = agent_ld(win);
      if (w != 0u) break;
      __builtin_amdgcn_s_sleep(8);
    }
    sh_bk = (w == xcc + 1u && slot < 32u) ? (int)slot : -1;
  }
  __syncthreads();
  const int bk = sh_bk;
  if (bk < 0) return;

  // ---- two-round sc0 probe (worker0 stores, worker31 polls same line twice) ----
  if (tid == 0) {
    if (bk == 0) {
      asm volatile("global_store_dword %0, %1, off sc0" :: "v"(probe), "v"(0x11111111u) : "memory");
      asm volatile("s_waitcnt vmcnt(0)" ::: "memory");
      agent_st(rdy1, 1u);
      uint32_t a;
      for (;;) { a = agent_ld(ack1); if (a != 0u) break; __builtin_amdgcn_s_sleep(4); }
      if (a == 1u) {
        asm volatile("global_store_dword %0, %1, off sc0" :: "v"(probe), "v"(0x22222222u) : "memory");
        asm volatile("s_waitcnt vmcnt(0)" ::: "memory");
        agent_st(rdy2, 1u);
      }
    } else if (bk == 31) {
      for (;;) { if (agent_ld(rdy1) != 0u) break; __builtin_amdgcn_s_sleep(4); }
      bool okA = false;
      for (int i = 0; i < 192 && !okA; ++i) {
        uint32_t pv;
        asm volatile("global_load_dword %0, %1, off sc0\n\ts_waitcnt vmcnt(0)"
                     : "=&v"(pv) : "v"(probe));
        okA = (pv == 0x11111111u);
        if (!okA) __builtin_amdgcn_s_sleep(2);
      }
      agent_st(ack1, okA ? 1u : 2u);
      bool okB = false;
      if (okA) {
        for (;;) { if (agent_ld(rdy2) != 0u) break; __builtin_amdgcn_s_sleep(4); }
        for (int i = 0; i < 192 && !okB; ++i) {
          uint32_t pv;
          asm volatile("global_load_dword %0, %1, off sc0\n\ts_waitcnt vmcnt(0)"
                       : "=&v"(pv) : "v"(probe));
          okB = (pv == 0x22222222u);
          if (!okB) __builtin_amdgcn_s_sleep(2);
        }
      }
      agent_st(verd, okB ? 1u : 2u);
    }
    uint32_t v;
    for (;;) { v = agent_ld(verd); if (v != 0u) break; __builtin_amdgcn_s_sleep(4); }
    sh_fast = (v == 1u);
  }
  __syncthreads();

  if (sh_fast)
    word_loop<true >(Whh, PW, hdat, flags, word_hs, h_lds, bk, tid);
  else
    word_loop<false>(Whh, PW, hdat, flags, word_hs, h_lds, bk, tid);
}

// ===================== tag projection + log_softmax =====================
__global__ __launch_bounds__(256) void k_tags(
    const short* __restrict__ word_hs, const float* __restrict__ Wt,
    const float* __restrict__ bt, float* __restrict__ out)
{
  __shared__ __align__(16) short Ws[64 * 256];   // 32KB: one K-half
  const int tid = threadIdx.x, lane = tid & 63, wid = tid >> 6;
  const int lo = lane & 15, hi = lane >> 4;
  const int n0 = blockIdx.x * 128;
  const int wb = n0 + wid * 32;

  f32x4 acc[4][2];
  #pragma unroll
  for (int fm = 0; fm < 4; ++fm)
    #pragma unroll
    for (int fn = 0; fn < 2; ++fn) acc[fm][fn] = (f32x4)0.0f;

  for (int half = 0; half < 2; ++half) {
    __syncthreads();
    for (int cid = tid; cid < 2048; cid += 256) {   // 64 rows x 32 chunks
      int row = cid >> 5, cp = cid & 31;
      int kch = cp ^ (row & 7);
      bf16x8 v;
      if (row < NT) {
        const float* src = &Wt[(size_t)row * KW + half * 256 + kch * 8];
        #pragma unroll
        for (int e = 0; e < 8; ++e) v[e] = f2bf(src[e]);
      } else v = (bf16x8)0;
      *(bf16x8*)&Ws[row * 256 + cp * 8] = v;
    }
    __syncthreads();
    #pragma unroll
    for (int kc = 0; kc < 8; ++kc) {
      bf16x8 bfr[2];
      #pragma unroll
      for (int fn = 0; fn < 2; ++fn) {
        int w = wb + fn * 16 + lo;
        bfr[fn] = *(const bf16x8*)&word_hs[(size_t)w * KW + half * 256 + kc * 32 + hi * 8];
      }
      #pragma unroll
      for (int fm = 0; fm < 4; ++fm) {
        int row = fm * 16 + lo;
        int ch = (kc * 4 + hi) ^ (row & 7);
        bf16x8 av = *(bf16x8*)&Ws[row * 256 + ch * 8];
        acc[fm][0] = MFMA16(av, bfr[0], acc[fm][0]);
        acc[fm][1] = MFMA16(av, bfr[1], acc[fm][1]);
      }
    }
  }

  #pragma unroll
  for (int fn = 0; fn < 2; ++fn) {
    int w = wb + fn * 16 + lo;
    float lg[16];
    float m = -1e30f;
    #pragma unroll
    for (int fm = 0; fm < 4; ++fm)
      #pragma unroll
      for (int q = 0; q < 4; ++q) {
        int tg = fm * 16 + hi * 4 + q;
        float bv = (tg < NT) ? bt[tg] : 0.0f;
        float v = acc[fm][fn][q] + bv;
        lg[fm * 4 + q] = v;
        if (tg < NT) m = fmaxf(m, v);
      }
    m = fmaxf(m, __shfl_xor(m, 16));
    m = fmaxf(m, __shfl_xor(m, 32));
    float s = 0.0f;
    #pragma unroll
    for (int fm = 0; fm < 4; ++fm)
      #pragma unroll
      for (int q = 0; q < 4; ++q) {
        int tg = fm * 16 + hi * 4 + q;
        if (tg < NT) s += __expf(lg[fm * 4 + q] - m);
      }
    s += __shfl_xor(s, 16);
    s += __shfl_xor(s, 32);
    float lz = m + __logf(s);
    #pragma unroll
    for (int fm = 0; fm < 4; ++fm)
      #pragma unroll
      for (int q = 0; q < 4; ++q) {
        int tg = fm * 16 + hi * 4 + q;
        if (tg < NT) out[(size_t)w * NT + tg] = lg[fm * 4 + q] - lz;
      }
  }
}

// ===================== launch =====================
extern "C" void kernel_launch(void* const* d_in, const int* in_sizes, int n_in,
                              void* d_out, int out_size, void* d_ws, size_t ws_size,
                              hipStream_t stream) {
  const int*   char_idx = (const int*)  d_in[0];
  const int*   word_idx = (const int*)  d_in[1];
  const float* char_emb = (const float*)d_in[2];
  const float* word_emb = (const float*)d_in[3];
  const float* Wc_ih    = (const float*)d_in[4];
  const float* Wc_hh    = (const float*)d_in[5];
  const float* bc       = (const float*)d_in[6];
  const float* Ww_ih    = (const float*)d_in[7];
  const float* Ww_hh    = (const float*)d_in[8];
  const float* bw       = (const float*)d_in[9];
  const float* Wt       = (const float*)d_in[10];
  const float* bt       = (const float*)d_in[11];
  float* out = (float*)d_out;

  const size_t MB = 1ull << 20;
  uint8_t* w8 = (uint8_t*)d_ws;
  float* PEb   = (float*)(w8 + 0);                 // 512K
  short* WhhC  = (short*)(w8 + 512 * 1024);        // 512K
  short* WihW  = (short*)(w8 + 1 * MB);            // 2M
  short* WhhW  = (short*)(w8 + 3 * MB);            // 2M
  float* bwI   = (float*)(w8 + 5 * MB);            // 8K
  uint8_t* xb  = (uint8_t*)(w8 + 5 * MB + 64 * 1024);  // 64K hdat + flags + control
  short* hA    = (short*)(w8 + 6 * MB);            // 16M
  short* hB    = (short*)(w8 + 22 * MB);           // 16M
  short* whs   = (short*)(w8 + 6 * MB);            // 32M (reuses hA/hB after k_xw)
  float* cC    = (float*)(w8 + 38 * MB);           // 32M
  short* Xw    = (short*)(w8 + 38 * MB);           // 32M (reuses cC after char steps)
  short* PW    = (short*)(w8 + 70 * MB);           // 128M

  k_prep_pe<<<128, 256, 0, stream>>>(char_emb, Wc_ih, bc, PEb);
  k_prep_w<<<2048, 256, 0, stream>>>(Wc_hh, Ww_ih, Ww_hh, bw, WhhC, WihW, WhhW, bwI);

  // char LSTM
  k_char0<<<NWRD, 256, 0, stream>>>(char_idx, PEb, cC, hA);
  for (int t = 1; t < NC; ++t) {
    short* src = (t & 1) ? hA : hB;
    short* dst = (t & 1) ? hB : hA;
    gemm_epi<256, 0><<<dim3(256, 8), 256, 0, stream>>>(
        WhhC, src, PEb, char_idx, t, cC, dst, nullptr, nullptr);
  }
  // h_12 ends in hB

  // word LSTM input projections for all timesteps
  k_xw<<<NWRD, 64, 0, stream>>>(word_idx, word_emb, hB, Xw);
  gemm_epi<512, 1><<<dim3(256, 16), 256, 0, stream>>>(
      WihW, Xw, nullptr, nullptr, 0, nullptr, nullptr, bwI, PW);

  // persistent recurrence: zero hdat slot0 (h_0=0), flags, election+probe control
  hipMemsetAsync(xb, 0, 67584, stream);
  k_word<<<256, 512, 0, stream>>>(WhhW, PW, xb, whs);

  // tags + log_softmax
  k_tags<<<256, 256, 0, stream>>>(whs, Wt, bt, out);
}